// Round 7
// baseline (318.329 us; speedup 1.0000x reference)
//
#include <hip/hip_runtime.h>
#include <cstddef>

// Problem constants
#define Bb 2
#define Cc_ 8
#define BINS 1024
#define Ww 512
#define HEADS 8
#define HD 128
#define NELEM (Bb*Cc_*BINS*Ww)   // 8388608
// workspace slot stride: skew by +640 elements (1280 B) to break the exact
// 16 MB power-of-2 alignment between the streamed buffers.
#define SLOT ((size_t)NELEM + 640)

typedef __attribute__((ext_vector_type(8)))  __bf16 bf16x8;
typedef __attribute__((ext_vector_type(4)))  __bf16 bf16x4;
typedef __attribute__((ext_vector_type(4)))  float  f32x4;
typedef __attribute__((ext_vector_type(16))) float  f32x16;
#define MFMA32(a,b,c) __builtin_amdgcn_mfma_f32_32x32x16_bf16(a,b,c,0,0,0)

// async global->LDS: lane i's 16B lands at ldsbase + i*16; global addr is a
// per-lane gather, so we pre-swizzle by computing the SOURCE of each slot.
__device__ __forceinline__ void async16(const __bf16* g, __bf16* l) {
    __builtin_amdgcn_global_load_lds(
        (const __attribute__((address_space(1))) void*)g,
        (__attribute__((address_space(3))) void*)l, 16, 0, 0);
}

__device__ __forceinline__ void phase_barrier() {
    asm volatile("s_waitcnt vmcnt(0) lgkmcnt(0)" ::: "memory");
    __builtin_amdgcn_s_barrier();
    __builtin_amdgcn_sched_barrier(0);
}

// ---------------------------------------------------------------------------
// Transpose-cast x -> xT [bc][w][i].  2048 blocks, one 64x64 tile each,
// nontemporal loads (x is read exactly once).
// ---------------------------------------------------------------------------
__global__ void __launch_bounds__(256) xpose(const float* __restrict__ x,
                                             __bf16* __restrict__ xT) {
    int b2 = blockIdx.x;                   // 0..2047
    int t = threadIdx.x;
    int w0 = (b2 & 7) * 64;
    int i0 = ((b2 >> 3) & 15) * 64;
    int bc = b2 >> 7;
    const float* src = x + (size_t)bc * BINS * Ww;
    __bf16* dst = xT + (size_t)bc * Ww * BINS;
    __shared__ float T[64][65];
    #pragma unroll
    for (int pass = 0; pass < 4; pass++) {
        int idx = t + pass * 256;
        int il = idx >> 4, ch = idx & 15;
        f32x4 v = __builtin_nontemporal_load(
            (const f32x4*)&src[(size_t)(i0 + il) * Ww + w0 + ch * 4]);
        T[il][ch * 4 + 0] = v[0]; T[il][ch * 4 + 1] = v[1];
        T[il][ch * 4 + 2] = v[2]; T[il][ch * 4 + 3] = v[3];
    }
    __syncthreads();
    #pragma unroll
    for (int pass = 0; pass < 2; pass++) {
        int idx = t + pass * 256;
        int wl = idx >> 3, ch = idx & 7;
        bf16x8 o;
        #pragma unroll
        for (int j = 0; j < 8; j++) o[j] = (__bf16)T[ch * 8 + j][wl];
        *(bf16x8*)&dst[(size_t)(w0 + wl) * BINS + i0 + ch * 8] = o;
    }
}

// ---------------------------------------------------------------------------
// bf16 GEMM, fused f32->bf16 A-cast, 64x64 TILES for occupancy.
// Grid was 512 blocks = 2/CU (grid-capped TLP, the round-4..6 bottleneck:
// MfmaUtil 14%, Occ 17%, latency exposed). Now: grid 2048 = 8/CU available,
// LDS 16KB, __launch_bounds__(256,4) -> 4 blocks/CU resident (16 waves/CU)
// so barrier drains overlap across blocks (m114 mechanism).
// Each of 4 waves computes one 32x32 quadrant. Simple 2-barrier phase
// (m97 lineage); A(t+1) f32 reg-load issued during compute(t), ds_write in
// next staging window (write-late).
// ---------------------------------------------------------------------------
template<bool BF16OUT>
__global__ void __launch_bounds__(256, 4) gemm32(const float* __restrict__ Wall,
                                                 const __bf16* __restrict__ Bt,
                                                 void* __restrict__ Yv) {
    int bc = blockIdx.z, c = bc & 7;
    const float*  A  = Wall + (size_t)c  * BINS * BINS;   // [m][k] f32
    const __bf16* Bm = Bt   + (size_t)bc * Ww * BINS;     // [n][k] bf16
    int n0 = blockIdx.x * 64, m0 = blockIdx.y * 64;

    __shared__ __align__(16) char smem[16384];
    __bf16* Asm = (__bf16*)smem;              // [64][64] bf16, swizzled chunks
    __bf16* Bsm = (__bf16*)(smem + 8192);

    int t = threadIdx.x, w = t >> 6;
    int l31 = t & 31, h = (t >> 5) & 1;
    int wm = w >> 1, wn = w & 1;

    // staging decode: slot p = j*256 + t (j=0,1) -> row p>>3, chunk (p&7)^(row&7)
    int rowS[2], colS[2];
    #pragma unroll
    for (int j = 0; j < 2; j++) {
        int p = j * 256 + t;
        int r = p >> 3, cs = (p & 7) ^ (r & 7);
        rowS[j] = r; colS[j] = cs * 8;
    }

    f32x16 acc;
    #pragma unroll
    for (int r = 0; r < 16; r++) acc[r] = 0.f;

    f32x4 alo[2], ahi[2];
    // prologue: A(0) -> regs
    #pragma unroll
    for (int j = 0; j < 2; j++) {
        const float* ap = A + (size_t)(m0 + rowS[j]) * BINS + colS[j];
        alo[j] = *(const f32x4*)ap;
        ahi[j] = *(const f32x4*)(ap + 4);
    }

    for (int ks = 0; ks < 16; ks++) {
        int k0 = ks * 64;
        __syncthreads();                       // LDS free for restage
        #pragma unroll
        for (int j = 0; j < 2; j++)
            async16(Bm + (size_t)(n0 + rowS[j]) * BINS + k0 + colS[j],
                    Bsm + (j * 256 + t) * 8);
        #pragma unroll
        for (int j = 0; j < 2; j++) {
            bf16x8 o = {(__bf16)alo[j][0], (__bf16)alo[j][1], (__bf16)alo[j][2], (__bf16)alo[j][3],
                        (__bf16)ahi[j][0], (__bf16)ahi[j][1], (__bf16)ahi[j][2], (__bf16)ahi[j][3]};
            *(bf16x8*)&Asm[(j * 256 + t) * 8] = o;
        }
        __syncthreads();                       // staging visible

        // issue A(t+1) f32 loads now; they retire during the MFMAs below
        if (ks + 1 < 16) {
            int k1 = k0 + 64;
            #pragma unroll
            for (int j = 0; j < 2; j++) {
                const float* ap = A + (size_t)(m0 + rowS[j]) * BINS + k1 + colS[j];
                alo[j] = *(const f32x4*)ap;
                ahi[j] = *(const f32x4*)(ap + 4);
            }
        }

        bf16x8 af[4], bfr[4];
        #pragma unroll
        for (int kc = 0; kc < 4; kc++) {
            int rowA = wm * 32 + l31;
            int chA = (kc * 2 + h) ^ (rowA & 7);
            af[kc] = *(bf16x8*)&Asm[rowA * 64 + chA * 8];
            int rowB = wn * 32 + l31;
            int chB = (kc * 2 + h) ^ (rowB & 7);
            bfr[kc] = *(bf16x8*)&Bsm[rowB * 64 + chB * 8];
        }
        #pragma unroll
        for (int kc = 0; kc < 4; kc++)
            acc = MFMA32(af[kc], bfr[kc], acc);
    }

    // epilogue: C/D reg map row = (reg&3)+8*(reg>>2)+4*h, col = l31.
    // Repack through LDS -> coalesced wide stores.
    __syncthreads();
    if constexpr (BF16OUT) {
        __bf16* Ob = (__bf16*)smem;         // [64][64] bf16 (8KB)
        __bf16* Cm = (__bf16*)Yv + (size_t)bc * BINS * Ww;
        #pragma unroll
        for (int reg = 0; reg < 16; reg++) {
            int ml = wm * 32 + (reg & 3) + 8 * (reg >> 2) + 4 * h;
            int nl = wn * 32 + l31;
            Ob[ml * 64 + nl] = (__bf16)acc[reg];
        }
        __syncthreads();
        #pragma unroll
        for (int pass = 0; pass < 2; pass++) {
            int idx = t + pass * 256;        // 0..511
            int row = idx >> 3, ch = idx & 7;
            *(bf16x8*)&Cm[(size_t)(m0 + row) * Ww + n0 + ch * 8] =
                *(bf16x8*)&Ob[row * 64 + ch * 8];
        }
    } else {
        float* Of = (float*)smem;           // [64][64] f32 (16KB)
        float* Cm = (float*)Yv + (size_t)bc * BINS * Ww;
        #pragma unroll
        for (int reg = 0; reg < 16; reg++) {
            int ml = wm * 32 + (reg & 3) + 8 * (reg >> 2) + 4 * h;
            int nl = wn * 32 + l31;
            Of[ml * 64 + nl] = acc[reg];
        }
        __syncthreads();
        #pragma unroll
        for (int pass = 0; pass < 4; pass++) {
            int idx = t + pass * 256;        // 0..1023
            int row = idx >> 4, c4 = idx & 15;
            __builtin_nontemporal_store(
                *(const f32x4*)&Of[row * 64 + c4 * 4],
                (f32x4*)&Cm[(size_t)(m0 + row) * Ww + n0 + c4 * 4]);
        }
    }
}

// ---------------------------------------------------------------------------
// cross-channel 1x3 conv + bias — register form, no LDS (unchanged).
// ---------------------------------------------------------------------------
__global__ void __launch_bounds__(256) conv1x3_reg(const __bf16* __restrict__ y,
                                                   const float* __restrict__ Wc,
                                                   const float* __restrict__ bias,
                                                   __bf16* __restrict__ vt) {
    int tid = blockIdx.x * 256 + threadIdx.x;
    int wc = tid & 63;
    int h  = (tid >> 6) & 1023;
    int b  = tid >> 16;
    int w0 = wc * 8;

    float ym[8][8], yl[8], yr[8];
    #pragma unroll
    for (int ci = 0; ci < 8; ci++) {
        const __bf16* row = y + ((size_t)(b * 8 + ci) * BINS + h) * Ww;
        bf16x8 v = *(const bf16x8*)&row[w0];
        #pragma unroll
        for (int j = 0; j < 8; j++) ym[ci][j] = (float)v[j];
        yl[ci] = (w0 > 0)   ? (float)row[w0 - 1] : 0.f;
        yr[ci] = (w0 < 504) ? (float)row[w0 + 8] : 0.f;
    }
    #pragma unroll
    for (int co = 0; co < 8; co++) {
        float acc[8];
        float bv = bias[co];
        #pragma unroll
        for (int j = 0; j < 8; j++) acc[j] = bv;
        #pragma unroll
        for (int ci = 0; ci < 8; ci++) {
            float wa = Wc[(co * 8 + ci) * 3 + 0];
            float wb = Wc[(co * 8 + ci) * 3 + 1];
            float wcc = Wc[(co * 8 + ci) * 3 + 2];
            acc[0] += yl[ci] * wa;
            #pragma unroll
            for (int j = 1; j < 8; j++) acc[j] += ym[ci][j - 1] * wa;
            #pragma unroll
            for (int j = 0; j < 8; j++) acc[j] += ym[ci][j] * wb;
            #pragma unroll
            for (int j = 0; j < 7; j++) acc[j] += ym[ci][j + 1] * wcc;
            acc[7] += yr[ci] * wcc;
        }
        bf16x8 o;
        #pragma unroll
        for (int j = 0; j < 8; j++) o[j] = (__bf16)acc[j];
        *(bf16x8*)&vt[((size_t)(b * 8 + co) * BINS + h) * Ww + w0] = o;
    }
}

// ---------------------------------------------------------------------------
// rotary + transpose: vt bf16 [bch][d][p] -> qrot bf16 [bch][p][d] (unchanged)
// ---------------------------------------------------------------------------
__global__ void __launch_bounds__(256) rotary_transpose(const __bf16* __restrict__ vt,
                                                        __bf16* __restrict__ qrot) {
    int p0  = blockIdx.x * 64;
    int bch = blockIdx.y;
    int t = threadIdx.x;
    __shared__ float T[64 * 129];   // [p_local][d]

    const __bf16* src = vt + (size_t)bch * HD * Ww;
    for (int pass = 0; pass < 4; pass++) {
        int idx = t + pass * 256;
        int d = idx >> 3, ch = idx & 7;
        bf16x8 v = *(const bf16x8*)&src[(size_t)d * Ww + p0 + ch * 8];
        #pragma unroll
        for (int j = 0; j < 8; j++) T[(ch * 8 + j) * 129 + d] = (float)v[j];
    }
    __syncthreads();
    for (int pass = 0; pass < 4; pass++) {
        int idx = t + pass * 256;
        int p = idx >> 4, chunk = idx & 15;
        float pos = (float)(p0 + p);
        bf16x8 o;
        if (chunk < 8) {
            #pragma unroll
            for (int j = 0; j < 8; j += 2) {
                int d = chunk * 8 + j;
                int jj = d >> 1;
                float inv = __expf(-(2.0f * jj / 64.0f) * 9.210340371976184f);
                float sn, cs;
                __sincosf(pos * inv, &sn, &cs);
                float x1 = T[p * 129 + d];
                float x2 = T[p * 129 + d + 1];
                o[j]     = (__bf16)(x1 * cs - x2 * sn);
                o[j + 1] = (__bf16)(x2 * cs + x1 * sn);
            }
        } else {
            #pragma unroll
            for (int j = 0; j < 8; j++)
                o[j] = (__bf16)T[p * 129 + chunk * 8 + j];
        }
        *(bf16x8*)&qrot[((size_t)bch * Ww + p0 + p) * HD + chunk * 8] = o;
    }
}

// ---------------------------------------------------------------------------
// Flash attention, 32x32x16 MFMA, S^T orientation, 2-phase double-buffered
// K/V staging (unchanged from round 5/6).
// ---------------------------------------------------------------------------
__global__ void __launch_bounds__(256, 2) attn32(const __bf16* __restrict__ qrot,
                                                 const __bf16* __restrict__ vt,
                                                 __bf16* __restrict__ attnT) {
    int bid = blockIdx.x;
    int bch = bid & 127, q0 = (bid >> 7) * 128;
    int t = threadIdx.x, wv = t >> 6, lane = t & 63;
    int l31 = lane & 31, h = lane >> 5;

    __shared__ __align__(16) char smem[81920];
    __bf16* KsB  = (__bf16*)smem;                       // [2][64*128]
    __bf16* VtsB = (__bf16*)(smem + 32768);             // [2][128*64]
    __bf16* Psw  = (__bf16*)(smem + 65536) + wv * 2048; // 32 qr x 64 kpos, per wave

    const __bf16* qb = qrot + (size_t)bch * Ww * HD;   // [p][d]
    const __bf16* vb = vt   + (size_t)bch * HD * Ww;   // [d][p]

    int qrow = q0 + wv * 32 + l31;
    bf16x8 qf[8];
    #pragma unroll
    for (int c = 0; c < 8; c++) {
        bf16x8 v = *(const bf16x8*)&qb[(size_t)qrow * HD + c * 16 + h * 8];
        #pragma unroll
        for (int j = 0; j < 8; j++) v[j] = (__bf16)((float)v[j] * 0.03125f);
        qf[c] = v;
    }

    f32x16 oacc[4];
    #pragma unroll
    for (int dt = 0; dt < 4; dt++)
        #pragma unroll
        for (int r = 0; r < 16; r++) oacc[dt][r] = 0.f;
    float m_st = -1e30f, l_st = 0.f;

    // ---- prologue: stage K/V tile 0 into buffer 0
    #pragma unroll
    for (int i = 0; i < 4; i++) {
        int p = wv * 256 + i * 64 + lane;
        int r  = p >> 4, cs  = ((p & 15) ^ (r & 15)) * 8;
        async16(qb + (size_t)r * HD + cs, KsB + (wv * 256 + i * 64) * 8);
        int r2 = p >> 3, cs2 = ((p & 7) ^ (r2 & 7)) * 8;
        async16(vb + (size_t)r2 * Ww + cs2, VtsB + (wv * 256 + i * 64) * 8);
    }
    phase_barrier();

    for (int kt = 0; kt < 8; kt++) {
        int cur = kt & 1, nxt = cur ^ 1;
        __bf16* Ks  = KsB  + cur * 8192;
        __bf16* Vts = VtsB + cur * 8192;

        // ---- issue next K/V tile's loads first
        if (kt < 7) {
            int k1 = (kt + 1) * 64;
            #pragma unroll
            for (int i = 0; i < 4; i++) {
                int p = wv * 256 + i * 64 + lane;
                int r  = p >> 4, cs  = ((p & 15) ^ (r & 15)) * 8;
                async16(qb + (size_t)(k1 + r) * HD + cs,
                        KsB + nxt * 8192 + (wv * 256 + i * 64) * 8);
                int r2 = p >> 3, cs2 = ((p & 7) ^ (r2 & 7)) * 8;
                async16(vb + (size_t)r2 * Ww + k1 + cs2,
                        VtsB + nxt * 8192 + (wv * 256 + i * 64) * 8);
            }
        }

        // ---- QK^T on current tile
        f32x16 st[2];
        #pragma unroll
        for (int t2 = 0; t2 < 2; t2++)
            #pragma unroll
            for (int r = 0; r < 16; r++) st[t2][r] = 0.f;
        #pragma unroll
        for (int c = 0; c < 8; c++)
            #pragma unroll
            for (int t2 = 0; t2 < 2; t2++) {
                int row = t2 * 32 + l31;
                int ch = (c * 2 + h) ^ (row & 15);
                bf16x8 ak = *(bf16x8*)&Ks[row * 128 + ch * 8];
                st[t2] = MFMA32(ak, qf[c], st[t2]);
            }

        // ---- online softmax (VALU phase also hides the staged loads)
        float mx = -1e30f;
        #pragma unroll
        for (int t2 = 0; t2 < 2; t2++)
            #pragma unroll
            for (int r = 0; r < 16; r++) mx = fmaxf(mx, st[t2][r]);
        mx = fmaxf(mx, __shfl_xor(mx, 32));
        float mnew = fmaxf(m_st, mx);
        float alpha = __expf(m_st - mnew);
        float sum = 0.f;
        #pragma unroll
        for (int t2 = 0; t2 < 2; t2++)
            #pragma unroll
            for (int r = 0; r < 16; r++) {
                float p = __expf(st[t2][r] - mnew);
                st[t2][r] = p;
                sum += p;
            }
        sum += __shfl_xor(sum, 32);
        l_st = l_st * alpha + sum;
        m_st = mnew;

        #pragma unroll
        for (int t2 = 0; t2 < 2; t2++)
            #pragma unroll
            for (int g = 0; g < 4; g++) {
                bf16x4 pk = {(__bf16)st[t2][4 * g],     (__bf16)st[t2][4 * g + 1],
                             (__bf16)st[t2][4 * g + 2], (__bf16)st[t2][4 * g + 3]};
                int ch = (t2 * 4 + g) ^ (l31 & 7);
                *(bf16x4*)&Psw[l31 * 64 + ch * 8 + 4 * h] = pk;
            }
        #pragma unroll
        for (int dt = 0; dt < 4; dt++)
            #pragma unroll
            for (int r = 0; r < 16; r++) oacc[dt][r] *= alpha;

        // ---- PV on current tile
        #pragma unroll
        for (int kc = 0; kc < 4; kc++) {
            int chp = (kc * 2 + h) ^ (l31 & 7);
            bf16x8 bp = *(bf16x8*)&Psw[l31 * 64 + chp * 8];
            #pragma unroll
            for (int dt = 0; dt < 4; dt++) {
                int row = dt * 32 + l31;
                int cv = (kc * 2 + h) ^ (row & 7);
                bf16x8 av = *(bf16x8*)&Vts[row * 64 + cv * 8];
                oacc[dt] = MFMA32(av, bp, oacc[dt]);
            }
        }

        phase_barrier();
    }

    __bf16* Ob = (__bf16*)smem + wv * 4096;   // 32 x 128 (chunk ^= qr&15), per wave
    float linv = 1.f / l_st;
    #pragma unroll
    for (int dt = 0; dt < 4; dt++)
        #pragma unroll
        for (int g = 0; g < 4; g++) {
            bf16x4 pk = {(__bf16)(oacc[dt][4 * g] * linv),
                         (__bf16)(oacc[dt][4 * g + 1] * linv),
                         (__bf16)(oacc[dt][4 * g + 2] * linv),
                         (__bf16)(oacc[dt][4 * g + 3] * linv)};
            int ch = (dt * 4 + g) ^ (l31 & 15);
            *(bf16x4*)&Ob[l31 * 128 + ch * 8 + 4 * h] = pk;
        }
    int bc = bch >> 3, h0 = bch & 7;
    #pragma unroll
    for (int i = 0; i < 8; i++) {
        int p = i * 64 + lane;
        int rr = p >> 4, cc = p & 15;
        int cs = cc ^ (rr & 15);
        bf16x8 v = *(bf16x8*)&Ob[rr * 128 + cs * 8];
        *(bf16x8*)&attnT[((size_t)bc * Ww + q0 + wv * 32 + rr) * BINS + h0 * HD + cc * 8] = v;
    }
}

// ---------------------------------------------------------------------------
// Launch. Workspace: 4 skewed slots (~67 MB).
//  S0 xT | S1 y(bf16) -> attnT | S2 vt | S3 qrot
// Weight casts are FUSED into the GEMMs (A staged from f32 directly).
// ---------------------------------------------------------------------------
extern "C" void kernel_launch(void* const* d_in, const int* in_sizes, int n_in,
                              void* d_out, int out_size, void* d_ws, size_t ws_size,
                              hipStream_t stream) {
    const float* x       = (const float*)d_in[0];
    const float* Wq_lin  = (const float*)d_in[1];
    const float* Wq_conv = (const float*)d_in[2];
    const float* bq_conv = (const float*)d_in[3];
    const float* Wout    = (const float*)d_in[4];
    float* out = (float*)d_out;

    __bf16* U = (__bf16*)d_ws;
    __bf16* xT      = U + 0 * SLOT;
    __bf16* y       = U + 1 * SLOT;
    __bf16* vtb     = U + 2 * SLOT;
    __bf16* qrot    = U + 3 * SLOT;
    __bf16* attnT   = U + 1 * SLOT;   // y dead after conv

    // 0. x transpose-cast
    xpose<<<dim3(2048), 256, 0, stream>>>(x, xT);
    // 1. y = Wq_lin @ x  (A cast fused; bf16 out). 64x64 tiles, 2048 blocks.
    gemm32<true><<<dim3(Ww / 64, BINS / 64, Bb * Cc_), 256, 0, stream>>>(Wq_lin, xT, y);
    // 2. vt = bf16(conv1x3(y) + bias)   (= V^T layout)
    conv1x3_reg<<<dim3(Bb * BINS * 64 / 256), 256, 0, stream>>>(y, Wq_conv, bq_conv, vtb);
    // 3. qrot = rotary(vt), transposed to [bch][p][d]
    rotary_transpose<<<dim3(Ww / 64, Bb * Cc_ * HEADS), 256, 0, stream>>>(vtb, qrot);
    // 4. attention -> attnT bf16 [bc][p][bins]
    attn32<<<dim3((Ww / 128) * 128), 256, 0, stream>>>(qrot, vtb, attnT);
    // 5. out = Wout @ attn  (A cast fused; f32 out). 64x64 tiles.
    gemm32<false><<<dim3(Ww / 64, BINS / 64, Bb * Cc_), 256, 0, stream>>>(Wout, attnT, out);
}

// Round 8
// 230.058 us; speedup vs baseline: 1.3837x; 1.3837x over previous
//
#include <hip/hip_runtime.h>
#include <cstddef>

// Problem constants
#define Bb 2
#define Cc_ 8
#define BINS 1024
#define Ww 512
#define HEADS 8
#define HD 128
#define NELEM (Bb*Cc_*BINS*Ww)   // 8388608
// workspace slot stride: skew by +640 elements (1280 B) to break the exact
// 16 MB power-of-2 alignment between the streamed buffers.
#define SLOT ((size_t)NELEM + 640)

typedef __attribute__((ext_vector_type(8)))  __bf16 bf16x8;
typedef __attribute__((ext_vector_type(4)))  __bf16 bf16x4;
typedef __attribute__((ext_vector_type(4)))  float  f32x4;
typedef __attribute__((ext_vector_type(16))) float  f32x16;
#define MFMA32(a,b,c) __builtin_amdgcn_mfma_f32_32x32x16_bf16(a,b,c,0,0,0)

// async global->LDS: lane i's 16B lands at ldsbase + i*16; global addr is a
// per-lane gather, so we pre-swizzle by computing the SOURCE of each slot.
__device__ __forceinline__ void async16(const __bf16* g, __bf16* l) {
    __builtin_amdgcn_global_load_lds(
        (const __attribute__((address_space(1))) void*)g,
        (__attribute__((address_space(3))) void*)l, 16, 0, 0);
}

// ---------------------------------------------------------------------------
// Weight cast f32->bf16 (Wq blocks 0..4095, Wout 4096..8191). Round-3 form
// (best measured total). Inputs read exactly once -> nontemporal.
// ---------------------------------------------------------------------------
__global__ void __launch_bounds__(256) wcast(const float* __restrict__ Wq,
                                             const float* __restrict__ Wout,
                                             __bf16* __restrict__ Wqb,
                                             __bf16* __restrict__ Woutb) {
    int bid = blockIdx.x;
    const float* in = (bid < 4096) ? Wq : Wout;
    __bf16* outp    = (bid < 4096) ? Wqb : Woutb;
    size_t i = ((size_t)(bid & 4095) * 256 + threadIdx.x) * 8;
    f32x4 a = __builtin_nontemporal_load((const f32x4*)&in[i]);
    f32x4 b = __builtin_nontemporal_load((const f32x4*)&in[i + 4]);
    bf16x8 o = {(__bf16)a[0], (__bf16)a[1], (__bf16)a[2], (__bf16)a[3],
                (__bf16)b[0], (__bf16)b[1], (__bf16)b[2], (__bf16)b[3]};
    *(bf16x8*)&outp[i] = o;
}

// ---------------------------------------------------------------------------
// Transpose-cast x -> xT [bc][w][i].  2048 blocks, one 64x64 tile each,
// nontemporal loads (x is read exactly once).
// ---------------------------------------------------------------------------
__global__ void __launch_bounds__(256) xpose(const float* __restrict__ x,
                                             __bf16* __restrict__ xT) {
    int b2 = blockIdx.x;                   // 0..2047
    int t = threadIdx.x;
    int w0 = (b2 & 7) * 64;
    int i0 = ((b2 >> 3) & 15) * 64;
    int bc = b2 >> 7;
    const float* src = x + (size_t)bc * BINS * Ww;
    __bf16* dst = xT + (size_t)bc * Ww * BINS;
    __shared__ float T[64][65];
    #pragma unroll
    for (int pass = 0; pass < 4; pass++) {
        int idx = t + pass * 256;
        int il = idx >> 4, ch = idx & 15;
        f32x4 v = __builtin_nontemporal_load(
            (const f32x4*)&src[(size_t)(i0 + il) * Ww + w0 + ch * 4]);
        T[il][ch * 4 + 0] = v[0]; T[il][ch * 4 + 1] = v[1];
        T[il][ch * 4 + 2] = v[2]; T[il][ch * 4 + 3] = v[3];
    }
    __syncthreads();
    #pragma unroll
    for (int pass = 0; pass < 2; pass++) {
        int idx = t + pass * 256;
        int wl = idx >> 3, ch = idx & 7;
        bf16x8 o;
        #pragma unroll
        for (int j = 0; j < 8; j++) o[j] = (__bf16)T[ch * 8 + j][wl];
        *(bf16x8*)&dst[(size_t)(w0 + wl) * BINS + i0 + ch * 8] = o;
    }
}

// ---------------------------------------------------------------------------
// bf16 GEMM, 32x32x16 MFMA, 128x128 tile, BK=64, **8 WAVES (512 threads)**.
// Round-3 structure (pure async16 A+B, 2-barrier phase, 32KB LDS) — best
// measured — with two changes:
//   * 8 waves/block: wave w = (wm = w>>2) m-half x (wn = w&3) n-quarter,
//     each wave 64x32 (2x1 of 32x32). Doubles waves/CU 8 -> 16 at the same
//     grid (512 blocks = 2/CU): more schedulable waves to cover the
//     per-phase barrier drain (m114 mechanism). VGPR ~100, bounds (512,4).
//   * XCD panel swizzle (round-6 proven: FETCH 82 -> 24.6 MB): all 8
//     sharers (4 n-tiles x 2 batches) of an A panel land on one XCD's L2.
// ---------------------------------------------------------------------------
template<bool BF16OUT>
__global__ void __launch_bounds__(512, 4) gemm32(const __bf16* __restrict__ Wall,
                                                 const __bf16* __restrict__ Bt,
                                                 void* __restrict__ Yv) {
    // XCD panel swizzle decode (bijective on 0..511)
    int lin = blockIdx.x;
    int k8  = lin & 7;           // XCD congruence class
    int q   = lin >> 3;
    int j8  = q & 7;             // sharer: n0i + 4*b
    int phi = q >> 3;
    int p   = phi * 8 + k8;      // panel id 0..63
    int c   = p & 7, m0 = (p >> 3) * 128;
    int n0  = (j8 & 3) * 128;
    int bc  = (j8 >> 2) * 8 + c;

    const __bf16* A  = Wall + (size_t)c  * BINS * BINS;   // [m][k]
    const __bf16* Bm = Bt   + (size_t)bc * Ww * BINS;     // [n][k]

    __shared__ __align__(16) char smem[32768];
    __bf16* Asm = (__bf16*)smem;            // 128 rows x 64 k (8 chunks of 16B)
    __bf16* Bsm = (__bf16*)(smem + 16384);

    int t = threadIdx.x, w = t >> 6, l = t & 63;
    int l31 = l & 31, h = (l >> 5) & 1;
    int wm = w >> 2, wn = w & 3;            // 2 m-halves x 4 n-quarters

    // staging decode: slot p2 = j*512 + t -> row p2>>3, chunk (p2&7)^(row&7)
    int rowS[2], colS[2];
    #pragma unroll
    for (int j = 0; j < 2; j++) {
        int p2 = j * 512 + t;
        int r = p2 >> 3, cs = (p2 & 7) ^ (r & 7);
        rowS[j] = r; colS[j] = cs * 8;
    }

    f32x16 acc[2];
    #pragma unroll
    for (int mt = 0; mt < 2; mt++)
        #pragma unroll
        for (int r = 0; r < 16; r++) acc[mt][r] = 0.f;

    for (int k0 = 0; k0 < BINS; k0 += 64) {
        __syncthreads();                    // previous compute done, LDS free
        #pragma unroll
        for (int j = 0; j < 2; j++) {
            async16(A  + (size_t)(m0 + rowS[j]) * BINS + k0 + colS[j],
                    Asm + (j * 512 + t) * 8);
            async16(Bm + (size_t)(n0 + rowS[j]) * BINS + k0 + colS[j],
                    Bsm + (j * 512 + t) * 8);
        }
        __syncthreads();                    // staging visible

        bf16x8 af[2][4], bfr[4];
        #pragma unroll
        for (int mt = 0; mt < 2; mt++)
            #pragma unroll
            for (int kc = 0; kc < 4; kc++) {
                int row = wm * 64 + mt * 32 + l31;
                int ch = (kc * 2 + h) ^ (row & 7);
                af[mt][kc] = *(bf16x8*)&Asm[row * 64 + ch * 8];
            }
        #pragma unroll
        for (int kc = 0; kc < 4; kc++) {
            int row = wn * 32 + l31;
            int ch = (kc * 2 + h) ^ (row & 7);
            bfr[kc] = *(bf16x8*)&Bsm[row * 64 + ch * 8];
        }
        #pragma unroll
        for (int kc = 0; kc < 4; kc++)
            #pragma unroll
            for (int mt = 0; mt < 2; mt++)
                acc[mt] = MFMA32(af[mt][kc], bfr[kc], acc[mt]);
    }

    // epilogue: C/D reg map row = (reg&3)+8*(reg>>2)+4*h, col = l31.
    __syncthreads();
    if constexpr (BF16OUT) {
        __bf16* Ob = (__bf16*)smem;         // [128][128] bf16 = 32 KB
        __bf16* Cm = (__bf16*)Yv + (size_t)bc * BINS * Ww;
        #pragma unroll
        for (int mt = 0; mt < 2; mt++)
            #pragma unroll
            for (int reg = 0; reg < 16; reg++) {
                int ml = wm * 64 + mt * 32 + (reg & 3) + 8 * (reg >> 2) + 4 * h;
                int nl = wn * 32 + l31;
                Ob[ml * 128 + nl] = (__bf16)acc[mt][reg];
            }
        __syncthreads();
        #pragma unroll
        for (int pass = 0; pass < 4; pass++) {
            int idx = t + pass * 512;        // 0..2047
            int row = idx >> 4, ch = idx & 15;
            *(bf16x8*)&Cm[(size_t)(m0 + row) * Ww + n0 + ch * 8] =
                *(bf16x8*)&Ob[row * 128 + ch * 8];
        }
    } else {
        float* Of = (float*)smem;           // [64][128] f32 = 32 KB per half
        float* Cm = (float*)Yv + (size_t)bc * BINS * Ww;
        #pragma unroll
        for (int half = 0; half < 2; half++) {
            if (wm == half) {
                #pragma unroll
                for (int mt = 0; mt < 2; mt++)
                    #pragma unroll
                    for (int reg = 0; reg < 16; reg++) {
                        int ml = mt * 32 + (reg & 3) + 8 * (reg >> 2) + 4 * h;
                        int nl = wn * 32 + l31;
                        Of[ml * 128 + nl] = acc[mt][reg];
                    }
            }
            __syncthreads();
            #pragma unroll
            for (int pass = 0; pass < 4; pass++) {
                int idx = t + pass * 512;    // 0..2047
                int row = idx >> 5, c4 = idx & 31;
                __builtin_nontemporal_store(
                    *(const f32x4*)&Of[row * 128 + c4 * 4],
                    (f32x4*)&Cm[(size_t)(m0 + half * 64 + row) * Ww + n0 + c4 * 4]);
            }
            __syncthreads();
        }
    }
}

// ---------------------------------------------------------------------------
// cross-channel 1x3 conv + bias — register form, no LDS (unchanged).
// ---------------------------------------------------------------------------
__global__ void __launch_bounds__(256) conv1x3_reg(const __bf16* __restrict__ y,
                                                   const float* __restrict__ Wc,
                                                   const float* __restrict__ bias,
                                                   __bf16* __restrict__ vt) {
    int tid = blockIdx.x * 256 + threadIdx.x;
    int wc = tid & 63;
    int h  = (tid >> 6) & 1023;
    int b  = tid >> 16;
    int w0 = wc * 8;

    float ym[8][8], yl[8], yr[8];
    #pragma unroll
    for (int ci = 0; ci < 8; ci++) {
        const __bf16* row = y + ((size_t)(b * 8 + ci) * BINS + h) * Ww;
        bf16x8 v = *(const bf16x8*)&row[w0];
        #pragma unroll
        for (int j = 0; j < 8; j++) ym[ci][j] = (float)v[j];
        yl[ci] = (w0 > 0)   ? (float)row[w0 - 1] : 0.f;
        yr[ci] = (w0 < 504) ? (float)row[w0 + 8] : 0.f;
    }
    #pragma unroll
    for (int co = 0; co < 8; co++) {
        float acc[8];
        float bv = bias[co];
        #pragma unroll
        for (int j = 0; j < 8; j++) acc[j] = bv;
        #pragma unroll
        for (int ci = 0; ci < 8; ci++) {
            float wa = Wc[(co * 8 + ci) * 3 + 0];
            float wb = Wc[(co * 8 + ci) * 3 + 1];
            float wcc = Wc[(co * 8 + ci) * 3 + 2];
            acc[0] += yl[ci] * wa;
            #pragma unroll
            for (int j = 1; j < 8; j++) acc[j] += ym[ci][j - 1] * wa;
            #pragma unroll
            for (int j = 0; j < 8; j++) acc[j] += ym[ci][j] * wb;
            #pragma unroll
            for (int j = 0; j < 7; j++) acc[j] += ym[ci][j + 1] * wcc;
            acc[7] += yr[ci] * wcc;
        }
        bf16x8 o;
        #pragma unroll
        for (int j = 0; j < 8; j++) o[j] = (__bf16)acc[j];
        *(bf16x8*)&vt[((size_t)(b * 8 + co) * BINS + h) * Ww + w0] = o;
    }
}

// ---------------------------------------------------------------------------
// rotary + transpose: vt bf16 [bch][d][p] -> qrot bf16 [bch][p][d] (unchanged)
// ---------------------------------------------------------------------------
__global__ void __launch_bounds__(256) rotary_transpose(const __bf16* __restrict__ vt,
                                                        __bf16* __restrict__ qrot) {
    int p0  = blockIdx.x * 64;
    int bch = blockIdx.y;
    int t = threadIdx.x;
    __shared__ float T[64 * 129];   // [p_local][d]

    const __bf16* src = vt + (size_t)bch * HD * Ww;
    for (int pass = 0; pass < 4; pass++) {
        int idx = t + pass * 256;
        int d = idx >> 3, ch = idx & 7;
        bf16x8 v = *(const bf16x8*)&src[(size_t)d * Ww + p0 + ch * 8];
        #pragma unroll
        for (int j = 0; j < 8; j++) T[(ch * 8 + j) * 129 + d] = (float)v[j];
    }
    __syncthreads();
    for (int pass = 0; pass < 4; pass++) {
        int idx = t + pass * 256;
        int p = idx >> 4, chunk = idx & 15;
        float pos = (float)(p0 + p);
        bf16x8 o;
        if (chunk < 8) {
            #pragma unroll
            for (int j = 0; j < 8; j += 2) {
                int d = chunk * 8 + j;
                int jj = d >> 1;
                float inv = __expf(-(2.0f * jj / 64.0f) * 9.210340371976184f);
                float sn, cs;
                __sincosf(pos * inv, &sn, &cs);
                float x1 = T[p * 129 + d];
                float x2 = T[p * 129 + d + 1];
                o[j]     = (__bf16)(x1 * cs - x2 * sn);
                o[j + 1] = (__bf16)(x2 * cs + x1 * sn);
            }
        } else {
            #pragma unroll
            for (int j = 0; j < 8; j++)
                o[j] = (__bf16)T[p * 129 + chunk * 8 + j];
        }
        *(bf16x8*)&qrot[((size_t)bch * Ww + p0 + p) * HD + chunk * 8] = o;
    }
}

// ---------------------------------------------------------------------------
// Flash attention, 32x32x16 MFMA, S^T orientation (round-3 version — part of
// the best-measured 235.1 configuration).
// ---------------------------------------------------------------------------
__global__ void __launch_bounds__(256, 2) attn32(const __bf16* __restrict__ qrot,
                                                 const __bf16* __restrict__ vt,
                                                 __bf16* __restrict__ attnT) {
    int bid = blockIdx.x;
    int bch = bid & 127, q0 = (bid >> 7) * 128;
    int t = threadIdx.x, wv = t >> 6, lane = t & 63;
    int l31 = lane & 31, h = lane >> 5;

    __shared__ __align__(16) char smem[49152];
    __bf16* Ks  = (__bf16*)smem;                        // 64 kpos x 128 d   (chunk ^= r&15)
    __bf16* Vts = (__bf16*)(smem + 16384);              // 128 d  x 64 kpos  (chunk ^= r&7)
    __bf16* Psw = (__bf16*)(smem + 32768) + wv * 2048;  // 32 qr x 64 kpos, per wave

    const __bf16* qb = qrot + (size_t)bch * Ww * HD;   // [p][d]
    const __bf16* vb = vt   + (size_t)bch * HD * Ww;   // [d][p]

    int qrow = q0 + wv * 32 + l31;
    bf16x8 qf[8];
    #pragma unroll
    for (int c = 0; c < 8; c++) {
        bf16x8 v = *(const bf16x8*)&qb[(size_t)qrow * HD + c * 16 + h * 8];
        #pragma unroll
        for (int j = 0; j < 8; j++) v[j] = (__bf16)((float)v[j] * 0.03125f);
        qf[c] = v;
    }

    f32x16 oacc[4];
    #pragma unroll
    for (int dt = 0; dt < 4; dt++)
        #pragma unroll
        for (int r = 0; r < 16; r++) oacc[dt][r] = 0.f;
    float m_st = -1e30f, l_st = 0.f;

    for (int kt = 0; kt < 8; kt++) {
        int k0 = kt * 64;
        __syncthreads();
        #pragma unroll
        for (int i = 0; i < 4; i++) {
            int p = wv * 256 + i * 64 + lane;
            int r  = p >> 4, cs  = ((p & 15) ^ (r & 15)) * 8;
            async16(qb + (size_t)(k0 + r) * HD + cs, Ks + (wv * 256 + i * 64) * 8);
            int r2 = p >> 3, cs2 = ((p & 7) ^ (r2 & 7)) * 8;
            async16(vb + (size_t)r2 * Ww + k0 + cs2, Vts + (wv * 256 + i * 64) * 8);
        }
        __syncthreads();

        f32x16 st[2];
        #pragma unroll
        for (int t2 = 0; t2 < 2; t2++)
            #pragma unroll
            for (int r = 0; r < 16; r++) st[t2][r] = 0.f;
        #pragma unroll
        for (int c = 0; c < 8; c++)
            #pragma unroll
            for (int t2 = 0; t2 < 2; t2++) {
                int row = t2 * 32 + l31;
                int ch = (c * 2 + h) ^ (row & 15);
                bf16x8 ak = *(bf16x8*)&Ks[row * 128 + ch * 8];
                st[t2] = MFMA32(ak, qf[c], st[t2]);
            }

        float mx = -1e30f;
        #pragma unroll
        for (int t2 = 0; t2 < 2; t2++)
            #pragma unroll
            for (int r = 0; r < 16; r++) mx = fmaxf(mx, st[t2][r]);
        mx = fmaxf(mx, __shfl_xor(mx, 32));
        float mnew = fmaxf(m_st, mx);
        float alpha = __expf(m_st - mnew);
        float sum = 0.f;
        #pragma unroll
        for (int t2 = 0; t2 < 2; t2++)
            #pragma unroll
            for (int r = 0; r < 16; r++) {
                float p = __expf(st[t2][r] - mnew);
                st[t2][r] = p;
                sum += p;
            }
        sum += __shfl_xor(sum, 32);
        l_st = l_st * alpha + sum;
        m_st = mnew;

        #pragma unroll
        for (int t2 = 0; t2 < 2; t2++)
            #pragma unroll
            for (int g = 0; g < 4; g++) {
                bf16x4 pk = {(__bf16)st[t2][4 * g],     (__bf16)st[t2][4 * g + 1],
                             (__bf16)st[t2][4 * g + 2], (__bf16)st[t2][4 * g + 3]};
                int ch = (t2 * 4 + g) ^ (l31 & 7);
                *(bf16x4*)&Psw[l31 * 64 + ch * 8 + 4 * h] = pk;
            }
        #pragma unroll
        for (int dt = 0; dt < 4; dt++)
            #pragma unroll
            for (int r = 0; r < 16; r++) oacc[dt][r] *= alpha;

        #pragma unroll
        for (int kc = 0; kc < 4; kc++) {
            int chp = (kc * 2 + h) ^ (l31 & 7);
            bf16x8 bp = *(bf16x8*)&Psw[l31 * 64 + chp * 8];
            #pragma unroll
            for (int dt = 0; dt < 4; dt++) {
                int row = dt * 32 + l31;
                int cv = (kc * 2 + h) ^ (row & 7);
                bf16x8 av = *(bf16x8*)&Vts[row * 64 + cv * 8];
                oacc[dt] = MFMA32(av, bp, oacc[dt]);
            }
        }
    }

    __syncthreads();
    __bf16* Ob = (__bf16*)smem + wv * 4096;   // 32 x 128 (chunk ^= qr&15)
    float linv = 1.f / l_st;
    #pragma unroll
    for (int dt = 0; dt < 4; dt++)
        #pragma unroll
        for (int g = 0; g < 4; g++) {
            bf16x4 pk = {(__bf16)(oacc[dt][4 * g] * linv),
                         (__bf16)(oacc[dt][4 * g + 1] * linv),
                         (__bf16)(oacc[dt][4 * g + 2] * linv),
                         (__bf16)(oacc[dt][4 * g + 3] * linv)};
            int ch = (dt * 4 + g) ^ (l31 & 15);
            *(bf16x4*)&Ob[l31 * 128 + ch * 8 + 4 * h] = pk;
        }
    int bc = bch >> 3, h0 = bch & 7;
    #pragma unroll
    for (int i = 0; i < 8; i++) {
        int p = i * 64 + lane;
        int rr = p >> 4, cc = p & 15;
        int cs = cc ^ (rr & 15);
        bf16x8 v = *(bf16x8*)&Ob[rr * 128 + cs * 8];
        *(bf16x8*)&attnT[((size_t)bc * Ww + q0 + wv * 32 + rr) * BINS + h0 * HD + cc * 8] = v;
    }
}

// ---------------------------------------------------------------------------
// Launch. Workspace: 6 skewed slots (~100.7 MB).
//  S0 Wq_bf | S1 xT | S2 Wout_bf | S3 y(bf16) -> attnT | S4 vt | S5 qrot
// ---------------------------------------------------------------------------
extern "C" void kernel_launch(void* const* d_in, const int* in_sizes, int n_in,
                              void* d_out, int out_size, void* d_ws, size_t ws_size,
                              hipStream_t stream) {
    const float* x       = (const float*)d_in[0];
    const float* Wq_lin  = (const float*)d_in[1];
    const float* Wq_conv = (const float*)d_in[2];
    const float* bq_conv = (const float*)d_in[3];
    const float* Wout    = (const float*)d_in[4];
    float* out = (float*)d_out;

    __bf16* U = (__bf16*)d_ws;
    __bf16* Wq_bf   = U + 0 * SLOT;
    __bf16* xT      = U + 1 * SLOT;
    __bf16* Wout_bf = U + 2 * SLOT;
    __bf16* y       = U + 3 * SLOT;
    __bf16* vtb     = U + 4 * SLOT;
    __bf16* qrot    = U + 5 * SLOT;
    __bf16* attnT   = U + 3 * SLOT;   // y dead after conv

    // 0a. weight casts
    wcast<<<dim3(8192), 256, 0, stream>>>(Wq_lin, Wout, Wq_bf, Wout_bf);
    // 0b. x transpose-cast
    xpose<<<dim3(2048), 256, 0, stream>>>(x, xT);
    // 1. y = Wq_lin @ x  (bf16 out). 128x128 tiles, 8 waves, XCD swizzle.
    gemm32<true><<<dim3(512), 512, 0, stream>>>(Wq_bf, xT, y);
    // 2. vt = bf16(conv1x3(y) + bias)   (= V^T layout)
    conv1x3_reg<<<dim3(Bb * BINS * 64 / 256), 256, 0, stream>>>(y, Wq_conv, bq_conv, vtb);
    // 3. qrot = rotary(vt), transposed to [bch][p][d]
    rotary_transpose<<<dim3(Ww / 64, Bb * Cc_ * HEADS), 256, 0, stream>>>(vtb, qrot);
    // 4. attention -> attnT bf16 [bc][p][bins]
    attn32<<<dim3((Ww / 128) * 128), 256, 0, stream>>>(qrot, vtb, attnT);
    // 5. out = Wout @ attn  (f32 out)
    gemm32<false><<<dim3(512), 512, 0, stream>>>(Wout_bf, attnT, out);
}